// Round 1
// 425.466 us; speedup vs baseline: 1.0298x; 1.0298x over previous
//
#include <hip/hip_runtime.h>

// SNN forward scan (LIF, Heaviside forward). T=2048, B=64, F=512.
// W is block-diagonal with 2x2 blocks -> per feature pair (f0,f0+1) the
// synapse is a 2x2 matvec; all other dot terms are exact fp32 zeros, so this
// is bitwise identical to the reference's full dot product.
//
// R7 theory: the ~2.5-2.8 TB/s plateau is Little's law on a single wave/CU:
// ~8 in-flight vmem entries x 512 B = 4 KB/CU outstanding; at ~375 ns HBM
// latency that is ~2.8 TB/s regardless of nominal software prefetch depth.
// The harness's own 1 GiB fill runs at 6.5 TB/s on this device, so DRAM is
// not the limit -- per-wave memory-level parallelism is.
//
// Fix: producer/consumer wave split (the canonical GEMM staging pattern).
// Per block: 4 producer waves stream x global->LDS (dwordx4, 8 loads deep
// each => ~32 KB in flight per CU, 8x the old cap), 1 compute wave runs the
// serial recurrence out of LDS and fires nontemporal stores it never waits
// on (the barrier store-drain hides under the producers' longer memory
// wait). Double-buffered LDS (2 x 64 steps x 512 B = 64 KiB), one
// __syncthreads per chunk, uniform control flow around every barrier.
// Compute arithmetic is instruction-identical to the previous passing
// kernel (same __fmul_rn/__fadd_rn order) -> bitwise-identical output.

typedef float v2f __attribute__((ext_vector_type(2)));
typedef float v4f __attribute__((ext_vector_type(4)));

constexpr int T_STEPS = 2048;
constexpr int B_DIM   = 64;
constexpr int F_DIM   = 512;
constexpr int BF      = B_DIM * F_DIM;          // 32768 floats per timestep
constexpr int BLK_FLOATS = 128;                 // floats per block per step (64 pairs)
constexpr int NBLK    = BF / BLK_FLOATS;        // 256 blocks (1 per CU)
constexpr int CHUNK   = 64;                     // timesteps per LDS buffer
constexpr int NCHUNK  = T_STEPS / CHUNK;        // 32
constexpr int NPROD   = 4;                      // producer waves per block
constexpr int STEPS_PER_PROD = CHUNK / NPROD;   // 16 steps per producer wave
constexpr int LOADS_PER_PROD = STEPS_PER_PROD / 2; // 8 dwordx4 insts (2 steps each)
constexpr int LDS_FLOATS = 2 * CHUNK * BLK_FLOATS; // 16384 floats = 64 KiB

__global__ __launch_bounds__(320, 1) void snn_scan_kernel(
    const float* __restrict__ x,
    const float* __restrict__ W,
    const float* __restrict__ leak_i,
    const float* __restrict__ leak_v,
    const float* __restrict__ thresh,
    float* __restrict__ out) {

    __shared__ float lds[LDS_FLOATS];

    const int tid  = threadIdx.x;
    const int wid  = tid >> 6;
    const int lane = tid & 63;
    const int blk  = blockIdx.x;
    const bool is_prod = (wid < NPROD);

    // ---------------- producer setup (waves 0..3) ----------------
    // One dwordx4 instruction covers 2 timesteps: lanes 0-31 -> step s
    // (contiguous 512 B slice of this block), lanes 32-63 -> step s+1.
    const int  half = lane >> 5;                 // 0 or 1
    const int  l32  = lane & 31;
    const int  sbase = wid * STEPS_PER_PROD + half;  // this lane's first step in chunk
    const float* xsrc = x + (size_t)blk * BLK_FLOATS + (size_t)l32 * 4;

    // ---------------- compute setup (wave 4) ----------------
    const int e  = blk * BLK_FLOATS + lane * 2;  // flat b*F + f0 (even)
    const int f0 = e & (F_DIM - 1);
    float w00 = 0.f, w01 = 0.f, w10 = 0.f, w11 = 0.f;
    float li0 = 0.f, li1 = 0.f, lv0 = 0.f, lv1 = 0.f, th0 = 0.f, th1 = 0.f;
    if (!is_prod) {
        w00 = W[(size_t)(f0    ) * F_DIM + f0    ];
        w01 = W[(size_t)(f0    ) * F_DIM + f0 + 1];
        w10 = W[(size_t)(f0 + 1) * F_DIM + f0    ];
        w11 = W[(size_t)(f0 + 1) * F_DIM + f0 + 1];
        li0 = leak_i[f0]; li1 = leak_i[f0 + 1];
        lv0 = leak_v[f0]; lv1 = leak_v[f0 + 1];
        th0 = thresh[f0]; th1 = thresh[f0 + 1];
    }
    float i0 = 0.f, v0 = 0.f, z0 = 0.f;   // even-f neuron state
    float i1 = 0.f, v1 = 0.f, z1 = 0.f;   // odd-f neuron state
    float* osrc = out + e;

    auto produce = [&](int c) {
        const int db = c & 1;
        const float* gb = xsrc + (size_t)(c * CHUNK + sbase) * BF;
        v4f r[LOADS_PER_PROD];
        #pragma unroll
        for (int i = 0; i < LOADS_PER_PROD; ++i)
            r[i] = __builtin_nontemporal_load(
                       (const v4f*)(gb + (size_t)(2 * i) * BF));
        float* lb = &lds[(size_t)db * (CHUNK * BLK_FLOATS)
                         + (size_t)sbase * BLK_FLOATS + (size_t)l32 * 4];
        #pragma unroll
        for (int i = 0; i < LOADS_PER_PROD; ++i)
            *(v4f*)(lb + (size_t)(2 * i) * BLK_FLOATS) = r[i];
    };

    auto consume = [&](int c) {
        const int db = c & 1;
        const float* lb = &lds[(size_t)db * (CHUNK * BLK_FLOATS) + (size_t)lane * 2];
        float* ob = osrc + (size_t)c * CHUNK * BF;
        #pragma unroll 8
        for (int j = 0; j < CHUNK; ++j) {
            const v2f xv = *(const v2f*)(lb + (size_t)j * BLK_FLOATS);
            const float xe = xv.x;
            const float xo = xv.y;
            // ff = 2x2 block matvec; remaining dot terms are exact zeros.
            const float ff0 = __fadd_rn(__fmul_rn(w00, xe), __fmul_rn(w01, xo));
            const float ff1 = __fadd_rn(__fmul_rn(w10, xe), __fmul_rn(w11, xo));
            // i_new = leak_i*i + ff
            i0 = __fadd_rn(__fmul_rn(li0, i0), ff0);
            i1 = __fadd_rn(__fmul_rn(li1, i1), ff1);
            // v_new = (leak_v*v)*(1-z) + i_new ; z in {0,1} -> select
            float vm0 = __fmul_rn(lv0, v0);
            float vm1 = __fmul_rn(lv1, v1);
            vm0 = (z0 > 0.0f) ? 0.0f : vm0;
            vm1 = (z1 > 0.0f) ? 0.0f : vm1;
            v0 = __fadd_rn(vm0, i0);
            v1 = __fadd_rn(vm1, i1);
            // z_new = heaviside(v_new - thresh) == (v_new > thresh)
            z0 = (v0 > th0) ? 1.0f : 0.0f;
            z1 = (v1 > th1) ? 1.0f : 0.0f;
            v2f zv; zv.x = z0; zv.y = z1;
            __builtin_nontemporal_store(zv, (v2f*)(ob + (size_t)j * BF));
        }
    };

    // Prologue: stage chunk 0. All barriers are in uniform control flow.
    if (is_prod) produce(0);
    __syncthreads();

    for (int c = 0; c < NCHUNK; ++c) {
        if (is_prod) {
            if (c + 1 < NCHUNK) produce(c + 1);
        } else {
            consume(c);
        }
        __syncthreads();
    }
}

extern "C" void kernel_launch(void* const* d_in, const int* in_sizes, int n_in,
                              void* d_out, int out_size, void* d_ws, size_t ws_size,
                              hipStream_t stream) {
    const float* x      = (const float*)d_in[0];
    const float* W      = (const float*)d_in[1];
    const float* leak_i = (const float*)d_in[2];
    const float* leak_v = (const float*)d_in[3];
    const float* thresh = (const float*)d_in[4];
    float* out = (float*)d_out;

    // 256 blocks x 320 threads: 4 producer waves + 1 compute wave per CU.
    snn_scan_kernel<<<dim3(NBLK), dim3(320), 0, stream>>>(
        x, W, leak_i, leak_v, thresh, out);
}